// Round 7
// baseline (2033.734 us; speedup 1.0000x reference)
//
#include <hip/hip_runtime.h>
#include <math.h>

#define HID 64
#define TST 2048
#define CH 16              // timesteps per chunk
#define NCH (TST / CH)     // 128 chunks
#define EPSN 1e-5f

#define REP64(M) \
  M(0) M(1) M(2) M(3) M(4) M(5) M(6) M(7) M(8) M(9) M(10) M(11) M(12) M(13) M(14) M(15) \
  M(16) M(17) M(18) M(19) M(20) M(21) M(22) M(23) M(24) M(25) M(26) M(27) M(28) M(29) M(30) M(31) \
  M(32) M(33) M(34) M(35) M(36) M(37) M(38) M(39) M(40) M(41) M(42) M(43) M(44) M(45) M(46) M(47) \
  M(48) M(49) M(50) M(51) M(52) M(53) M(54) M(55) M(56) M(57) M(58) M(59) M(60) M(61) M(62) M(63)

// ---------------------------------------------------------------------------
// Kernel 1: x = GELU(LayerNorm(ce @ w1 + b1))  -> staged into d_out (unchanged)
// ---------------------------------------------------------------------------
__global__ void k_inproj(const float* __restrict__ ce, const float* __restrict__ w1,
                         const float* __restrict__ b1, const float* __restrict__ g1,
                         const float* __restrict__ be1, float* __restrict__ xout,
                         int nrows) {
    const int lane = threadIdx.x & 63;
    const int wave = threadIdx.x >> 6;
    const long row = (long)blockIdx.x * 4 + wave;
    if (row >= nrows) return;
    const float* cr = ce + row * 6;
    float acc = b1[lane];
    acc += cr[0] * w1[0 * HID + lane];
    acc += cr[1] * w1[1 * HID + lane];
    acc += cr[2] * w1[2 * HID + lane];
    acc += cr[3] * w1[3 * HID + lane];
    acc += cr[4] * w1[4 * HID + lane];
    acc += cr[5] * w1[5 * HID + lane];
    float s = acc;
#pragma unroll
    for (int m = 32; m >= 1; m >>= 1) s += __shfl_xor(s, m, 64);
    const float mean = s * (1.0f / 64.0f);
    const float d = acc - mean;
    float q = d * d;
#pragma unroll
    for (int m = 32; m >= 1; m >>= 1) q += __shfl_xor(q, m, 64);
    const float var = q * (1.0f / 64.0f);
    const float xn = d * rsqrtf(var + EPSN) * g1[lane] + be1[lane];
    const float ge = 0.5f * xn * (1.0f + erff(xn * 0.70710678118654752440f));
    xout[row * HID + lane] = ge;
}

// Identical GRU combine for every wave that tracks h (bitwise-deterministic).
__device__ __forceinline__ float gru_step(float gr, float gz, float gn,
                                          float pr, float pz, float pn, float h) {
    const float r = 1.0f / (1.0f + __expf(-(gr + pr)));
    const float z = 1.0f / (1.0f + __expf(-(gz + pz)));
    const float pre = gn + r * pn;
    const float e2 = __expf(2.0f * pre);
    const float n = 1.0f - 2.0f / (e2 + 1.0f);
    return (1.0f - z) * n + z * h;
}

// ---------------------------------------------------------------------------
// Kernel 2: GRU scan, 8 waves, one gate per wave.
//
// R6 resubmit (R6 bench was an infra failure: container acquire died, no
// kernel verdict). Theory unchanged from R5 post-mortem:
//
// All matvec operand BROADCASTS moved off the LDS pipe. Evidence: R0-R5
// (5 different register/sync structures, incl. verified AGPR-resident
// weights in R5: VGPR_Count 92 = 28 arch + 64 acc) ALL land at 1830-1880
// cy/step. The shared invariant is ~230 wave-uniform ds_read_b64 per step
// (hv/xv/hr broadcasts) x ~6 cy LDS-pipe occupancy ~= 1400 cy/step: the
// LDS pipe is the serializer (invisible to every captured counter;
// VALUBusy 29% is just the fill). Fix: operand vectors stay
// lane-distributed in ONE VGPR (h_reg already is; x row / hist row become
// one per-lane ds_read_b32), and the matvec is 64x { v_readlane -> SGPR,
// v_fmac_f32 vacc, s_hj, v_Wj } — zero LDS traffic. Remaining LDS ops
// ~40 per-lane b32/step. hb[] broadcast buffer deleted. Weights: 64 named
// floats, AGPR-pinned ("+a", the R5-proven mechanism). Wave 7's x
// prefetch split issue@t=0 / store@t=4 to hide HBM latency.
//   waves 0-2: W_hh gate rows — redundant combine + readlane matvec.
//   waves 3-5: W_ih gate rows — gi for step s+16 -> gibuf.
//   wave 6:    w2 column — LN epilogue on quad-buffered hist.
//   wave 7:    4th redundant combine -> hist; split x prefetch.
// One __syncthreads per timestep paces all cross-wave handoffs.
// ---------------------------------------------------------------------------
__global__ __launch_bounds__(512, 2)
void k_gru(float* xo,
           const float* __restrict__ W_ih, const float* __restrict__ b_ih,
           const float* __restrict__ W_hh, const float* __restrict__ b_hh,
           const float* __restrict__ w2, const float* __restrict__ b2,
           const float* __restrict__ g2, const float* __restrict__ be2) {
    __shared__ __align__(16) float4 xbuf[2][CH][16];    // 8 KB   x chunks
    __shared__ __align__(16) float gibuf[2][CH][192];   // 24 KB  gi preacts
    __shared__ __align__(16) float hist[4][CH][HID];    // 16 KB  h history (quad)
    __shared__ __align__(16) float part[2][3][HID];     // 1.5 KB gate partials (dbuf)
    __shared__ __align__(16) float ybuf[2][8][HID];     // 4 KB   epilogue y staging

    const int tid = threadIdx.x;
    const int lane = tid & 63;
    const int wv = tid >> 6;
    float* xb = xo + (size_t)blockIdx.x * TST * HID;

#define DECLW(j) float W##j = 0.f;
    REP64(DECLW)
    float bh = 0.f, b2r = 0.f, g2r = 0.f, be2r = 0.f;

    if (wv < 6) {
        const float* wbp = (wv < 3) ? (W_hh + (size_t)(wv * 64 + lane) * HID)
                                    : (W_ih + (size_t)((wv - 3) * 64 + lane) * HID);
#define LWR(j) W##j = wbp[j];
        REP64(LWR)
        bh = (wv < 3) ? b_hh[wv * 64 + lane] : b_ih[(wv - 3) * 64 + lane];
    } else if (wv == 6) {
#define LW6(j) W##j = w2[(size_t)(j) * HID + lane];
        REP64(LW6)
        b2r = b2[lane]; g2r = g2[lane]; be2r = be2[lane];
    }
    // Park every weight in the AGPR file (R5-verified residency mechanism).
#define PINW(j) asm volatile("" : "+a"(W##j));
    REP64(PINW)

    // Prefill: x chunk 0, initial partials (W·h(-1)+b = b), h0 = 0.
    if (tid < 256) ((float4*)&xbuf[0][0][0])[tid] = ((const float4*)xb)[tid];
    if (wv < 3) part[0][wv][lane] = bh;
    float h_reg = 0.f;
    float pown = bh;   // scan wave's own-gate partial (register copy of part[])
    float4 pf0 = {0,0,0,0}, pf1 = {0,0,0,0}, pf2 = {0,0,0,0}, pf3 = {0,0,0,0};
    __syncthreads();

    // readlane matvec: operand vector lane-distributed in hsI (bit-cast),
    // weights in W0..W63; 4 accumulators, deterministic order for all waves.
#define MACJ(j) { const float hj = __int_as_float(__builtin_amdgcn_readlane(hsI, j)); \
                  if (((j) & 3) == 0)      a0 = fmaf(hj, W##j, a0); \
                  else if (((j) & 3) == 1) a1 = fmaf(hj, W##j, a1); \
                  else if (((j) & 3) == 2) a2 = fmaf(hj, W##j, a2); \
                  else                     a3 = fmaf(hj, W##j, a3); }

#define LNR4(slot, ub, chk, rbase) { \
    float yv[4], sv[4], qv[4]; \
    _Pragma("unroll") for (int u = 0; u < 4; ++u) yv[u] = ybuf[slot][(ub) + u][lane]; \
    _Pragma("unroll") for (int u = 0; u < 4; ++u) { sv[u] = yv[u]; qv[u] = yv[u] * yv[u]; } \
    _Pragma("unroll") for (int m = 32; m >= 1; m >>= 1) { \
        _Pragma("unroll") for (int u = 0; u < 4; ++u) sv[u] += __shfl_xor(sv[u], m, 64); \
        _Pragma("unroll") for (int u = 0; u < 4; ++u) qv[u] += __shfl_xor(qv[u], m, 64); } \
    _Pragma("unroll") for (int u = 0; u < 4; ++u) { \
        const float mean = sv[u] * (1.0f / 64.0f); \
        const float var = qv[u] * (1.0f / 64.0f) - mean * mean; \
        const float dd = yv[u] - mean; \
        xb[(size_t)((chk) * CH + (rbase) + u) * HID + lane] = \
            dd * rsqrtf(var + EPSN) * g2r + be2r; } }

    for (int s = -16; s <= 2081; ++s) {
        const int c = s >> 4;      // arithmetic shift: correct for s<0
        const int t = s & 15;
        if (wv < 3) {
            // ---- scan gate wv: combine + readlane matvec for step s ----
            if (s >= 0 && s < TST) {
                const float* gp = &gibuf[c & 1][t][0];
                const float gr = gp[lane], gz = gp[64 + lane], gn = gp[128 + lane];
                float pr, pz, pn;
                if (wv == 0)      { pr = pown;                 pz = part[s & 1][1][lane]; pn = part[s & 1][2][lane]; }
                else if (wv == 1) { pr = part[s & 1][0][lane]; pz = pown;                 pn = part[s & 1][2][lane]; }
                else              { pr = part[s & 1][0][lane]; pz = part[s & 1][1][lane]; pn = pown; }
                h_reg = gru_step(gr, gz, gn, pr, pz, pn, h_reg);
                const int hsI = __float_as_int(h_reg);
                float a0 = 0.f, a1 = 0.f, a2 = 0.f, a3 = 0.f;
                REP64(MACJ)
                pown = ((a0 + a1) + (a2 + a3)) + bh;         // partial for step s+1
                part[(s + 1) & 1][wv][lane] = pown;
            }
        } else if (wv < 6) {
            // ---- gi gate (wv-3) for step s+16: per-lane x read + readlane matvec ----
            if (s < TST - CH) {
                const int sf = s + CH;
                const float xr = ((const float*)&xbuf[(sf >> 4) & 1][sf & 15][0])[lane];
                const int hsI = __float_as_int(xr);
                float a0 = 0.f, a1 = 0.f, a2 = 0.f, a3 = 0.f;
                REP64(MACJ)
                gibuf[(sf >> 4) & 1][sf & 15][(wv - 3) * 64 + lane] =
                    ((a0 + a1) + (a2 + a3)) + bh;
            }
        } else if (wv == 6) {
            // ---- epilogue: y-dot row t of chunk c-2 (readlane matvec) ----
            if (s >= 32 && c <= 129) {
                const float hrow = hist[(c - 2) & 3][t][lane];
                const int hsI = __float_as_int(hrow);
                float a0 = 0.f, a1 = 0.f, a2 = 0.f, a3 = 0.f;
                REP64(MACJ)
                ybuf[t >> 3][t & 7][lane] = b2r + ((a0 + a1) + (a2 + a3));
            }
            if ((t == 8 || t == 9) && c >= 2 && c <= 129) {
                const int ub = (t - 8) * 4;
                LNR4(0, ub, c - 2, ub)              // rows 0-3 / 4-7 of chunk c-2
            }
            if ((t == 0 || t == 1) && c >= 3 && c <= 130) {
                const int ub = t * 4;
                LNR4(1, ub, c - 3, 8 + ub)          // rows 8-11 / 12-15 of chunk c-3
            }
        } else {
            // ---- wave 7: 4th combine -> hist; split x prefetch ----
            if (s >= 0 && s < TST) {
                const float* gp = &gibuf[c & 1][t][0];
                const float pr = part[s & 1][0][lane];
                const float pz = part[s & 1][1][lane];
                const float pn = part[s & 1][2][lane];
                h_reg = gru_step(gp[lane], gp[64 + lane], gp[128 + lane], pr, pz, pn, h_reg);
                hist[c & 3][t][lane] = h_reg;
            }
            if (t == 0 && c >= -1 && c <= 125) {
                // issue loads for x chunk c+2 (HBM latency hides under 4 steps)
                const float4* src = (const float4*)(xb + (size_t)(c + 2) * CH * HID);
                pf0 = src[lane]; pf1 = src[lane + 64];
                pf2 = src[lane + 128]; pf3 = src[lane + 192];
            }
            if (t == 4 && c >= -1 && c <= 125) {
                // land them in xbuf slot (c+2)&1 == c&1 (consumers start next chunk)
                float4* dst = (float4*)&xbuf[c & 1][0][0];
                dst[lane] = pf0; dst[lane + 64] = pf1;
                dst[lane + 128] = pf2; dst[lane + 192] = pf3;
            }
        }
        __syncthreads();
    }
}

extern "C" void kernel_launch(void* const* d_in, const int* in_sizes, int n_in,
                              void* d_out, int out_size, void* d_ws, size_t ws_size,
                              hipStream_t stream) {
    const float* ce  = (const float*)d_in[0];
    const float* w1  = (const float*)d_in[1];
    const float* b1  = (const float*)d_in[2];
    const float* g1  = (const float*)d_in[3];
    const float* be1 = (const float*)d_in[4];
    const float* Wih = (const float*)d_in[5];
    const float* bih = (const float*)d_in[6];
    const float* Whh = (const float*)d_in[7];
    const float* bhh = (const float*)d_in[8];
    const float* w2  = (const float*)d_in[9];
    const float* b2  = (const float*)d_in[10];
    const float* g2  = (const float*)d_in[11];
    const float* be2 = (const float*)d_in[12];
    float* out = (float*)d_out;

    const int nrows = in_sizes[0] / 6;   // B*T
    const int B = nrows / TST;           // 256

    k_inproj<<<(nrows + 3) / 4, 256, 0, stream>>>(ce, w1, b1, g1, be1, out, nrows);
    k_gru<<<B, 512, 0, stream>>>(out, Wih, bih, Whh, bhh, w2, b2, g2, be2);
}

// Round 8
// 1722.158 us; speedup vs baseline: 1.1809x; 1.1809x over previous
//
#include <hip/hip_runtime.h>
#include <math.h>

#define HID 64
#define TST 2048
#define CH 16              // timesteps per chunk
#define NCH (TST / CH)     // 128 chunks
#define EPSN 1e-5f

typedef float v2f __attribute__((ext_vector_type(2)));

#define REP32(M) M(0) M(1) M(2) M(3) M(4) M(5) M(6) M(7) \
                 M(8) M(9) M(10) M(11) M(12) M(13) M(14) M(15) \
                 M(16) M(17) M(18) M(19) M(20) M(21) M(22) M(23) \
                 M(24) M(25) M(26) M(27) M(28) M(29) M(30) M(31)

// ---------------------------------------------------------------------------
// Kernel 1: x = GELU(LayerNorm(ce @ w1 + b1))  -> staged into d_out (unchanged)
// ---------------------------------------------------------------------------
__global__ void k_inproj(const float* __restrict__ ce, const float* __restrict__ w1,
                         const float* __restrict__ b1, const float* __restrict__ g1,
                         const float* __restrict__ be1, float* __restrict__ xout,
                         int nrows) {
    const int lane = threadIdx.x & 63;
    const int wave = threadIdx.x >> 6;
    const long row = (long)blockIdx.x * 4 + wave;
    if (row >= nrows) return;
    const float* cr = ce + row * 6;
    float acc = b1[lane];
    acc += cr[0] * w1[0 * HID + lane];
    acc += cr[1] * w1[1 * HID + lane];
    acc += cr[2] * w1[2 * HID + lane];
    acc += cr[3] * w1[3 * HID + lane];
    acc += cr[4] * w1[4 * HID + lane];
    acc += cr[5] * w1[5 * HID + lane];
    float s = acc;
#pragma unroll
    for (int m = 32; m >= 1; m >>= 1) s += __shfl_xor(s, m, 64);
    const float mean = s * (1.0f / 64.0f);
    const float d = acc - mean;
    float q = d * d;
#pragma unroll
    for (int m = 32; m >= 1; m >>= 1) q += __shfl_xor(q, m, 64);
    const float var = q * (1.0f / 64.0f);
    const float xn = d * rsqrtf(var + EPSN) * g1[lane] + be1[lane];
    const float ge = 0.5f * xn * (1.0f + erff(xn * 0.70710678118654752440f));
    xout[row * HID + lane] = ge;
}

// ---------------------------------------------------------------------------
// Kernel 2: GRU scan, wave-specialized, chunk-phased (R3 structure) with
// AGPR-resident weights (R5-proven "+a" pin).
//
// Evidence trail: R5 (8-wave, per-step barrier, AGPR weights) floor =
// 1870 cy/step = barrier + cross-wave LDS handoff paid every step; R7
// (readlane matvec) refuted the LDS-pipe theory (removed 90% of LDS ops,
// got SLOWER: +VALU issue dominates). R3 (this chunked structure, NO
// per-step barrier: scan chain = hbuf roundtrip + combine + 96 pk_fma
// issue ~= 460 cy/step) measured 1880 cy/step ONLY because its 192-reg
// W_hh set was rematerialized from L2 every step (VGPR_Count 132).
// This round: R3 byte-identical + "+a" pins -> weights in the AGPR
// class (192 AGPRs, separate from the 256-VGPR arch class; 1 wave/SIMD
// via waves_per_eu(1,1) gives the full 512-reg unified budget, so RA
// has no pressure-reason to spill).
//   wave 0: A=W_hh r-rows, B=z-rows, C=n-rows (192 AGPRs), serial scan,
//           h via intra-wave LDS broadcast, no barriers inside a chunk.
//   wave 1: A=W_ih r-rows, B=W_ih n-rows (128 AGPRs), gi chunk p+1.
//   wave 2: A=W_ih z-rows (64 AGPRs), gi chunk p+1.
//   wave 3: A=w2 column (64 AGPRs), LN epilogue chunk p-2 + x prefetch.
// ---------------------------------------------------------------------------
__global__ __launch_bounds__(256, 1)
__attribute__((amdgpu_waves_per_eu(1, 1)))
void k_gru(float* xo,
           const float* __restrict__ W_ih, const float* __restrict__ b_ih,
           const float* __restrict__ W_hh, const float* __restrict__ b_hh,
           const float* __restrict__ w2, const float* __restrict__ b2,
           const float* __restrict__ g2, const float* __restrict__ be2) {
    __shared__ __align__(16) float4 xbuf[2][CH][16];    // 8 KB  x chunks
    __shared__ __align__(16) float gibuf[2][CH][192];   // 24 KB gi preacts
    __shared__ __align__(16) float hist[2][CH][HID];    // 8 KB  h history
    __shared__ __align__(16) float hbuf[HID];           // h broadcast (wave 0)

    const int tid = threadIdx.x;
    const int lane = tid & 63;
    const int wv = tid >> 6;
    float* xb = xo + (size_t)blockIdx.x * TST * HID;

#define DECLW(i) v2f A##i = {0.f, 0.f}, B##i = {0.f, 0.f}, C##i = {0.f, 0.f};
    REP32(DECLW)
    float sc0 = 0.f, sc1 = 0.f, sc2 = 0.f;   // per-wave scalar params

    if (wv == 0) {
        const v2f* r0 = (const v2f*)(W_hh + (size_t)lane * HID);
        const v2f* r1 = (const v2f*)(W_hh + (size_t)(64 + lane) * HID);
        const v2f* r2 = (const v2f*)(W_hh + (size_t)(128 + lane) * HID);
#define LW0(i) A##i = r0[i]; B##i = r1[i]; C##i = r2[i];
        REP32(LW0)
        sc0 = b_hh[lane]; sc1 = b_hh[64 + lane]; sc2 = b_hh[128 + lane];
        hbuf[lane] = 0.0f;
    } else if (wv == 1) {
        const v2f* rA = (const v2f*)(W_ih + (size_t)lane * HID);
        const v2f* rB = (const v2f*)(W_ih + (size_t)(128 + lane) * HID);
#define LW1(i) A##i = rA[i]; B##i = rB[i];
        REP32(LW1)
        sc0 = b_ih[lane]; sc1 = b_ih[128 + lane];
    } else if (wv == 2) {
        const v2f* rC = (const v2f*)(W_ih + (size_t)(64 + lane) * HID);
#define LW2(i) A##i = rC[i];
        REP32(LW2)
        sc0 = b_ih[64 + lane];
    } else {
#define LW3(i) A##i.x = w2[(size_t)(2 * (i)) * HID + lane]; \
               A##i.y = w2[(size_t)(2 * (i) + 1) * HID + lane];
        REP32(LW3)
        sc0 = b2[lane]; sc1 = g2[lane]; sc2 = be2[lane];
    }

    // Park every weight pair in the AGPR file (R5-proven residency
    // mechanism: AGPR class is separate from the arch-VGPR class; no
    // memory path, no remat-by-reload).
#define PINW(i) asm volatile("" : "+a"(A##i), "+a"(B##i), "+a"(C##i));
    REP32(PINW)

    {
        const float4* src = (const float4*)xb;
        ((float4*)xbuf[0])[tid] = src[tid];
    }
    float h_reg = 0.0f;
    __syncthreads();

    for (int p = 0; p <= NCH + 1; ++p) {
        if (wv == 0) {
            if (p >= 1 && p <= NCH) {
                const int c = p - 1;
                const float* gp = (const float*)gibuf[c & 1];
                float* hp = (float*)hist[c & 1];
                for (int t = 0; t < CH; ++t) {
                    const float gr = gp[t * 192 + lane];
                    const float gz = gp[t * 192 + 64 + lane];
                    const float gn = gp[t * 192 + 128 + lane];
                    const v2f* hv = (const v2f*)hbuf;
                    // 2-way split accumulators: halve the dependent FMA chain
                    v2f ar0 = {0.f, 0.f}, ar1 = {0.f, 0.f};
                    v2f az0 = {0.f, 0.f}, az1 = {0.f, 0.f};
                    v2f an0 = {0.f, 0.f}, an1 = {0.f, 0.f};
#define SFMA(i) { const v2f h2 = hv[i]; \
                  if ((i) & 1) { ar1 += A##i * h2; az1 += B##i * h2; an1 += C##i * h2; } \
                  else         { ar0 += A##i * h2; az0 += B##i * h2; an0 += C##i * h2; } }
                    REP32(SFMA)
                    const v2f arv = ar0 + ar1;
                    const v2f azv = az0 + az1;
                    const v2f anv = an0 + an1;
                    const float rpre = gr + arv.x + arv.y + sc0;
                    const float zpre = gz + azv.x + azv.y + sc1;
                    const float hn = anv.x + anv.y + sc2;
                    const float r = 1.0f / (1.0f + __expf(-rpre));
                    const float z = 1.0f / (1.0f + __expf(-zpre));
                    const float pre = gn + r * hn;
                    const float e2 = __expf(2.0f * pre);
                    const float n = 1.0f - 2.0f / (e2 + 1.0f);
                    h_reg = (1.0f - z) * n + z * h_reg;
                    hbuf[lane] = h_reg;
                    hp[t * HID + lane] = h_reg;
                }
            }
        } else if (wv == 1 || wv == 2) {
            if (p < NCH) {
                const float4* xc = (const float4*)xbuf[p & 1];
                float* gp = (float*)gibuf[p & 1];
                for (int t = 0; t < CH; ++t) {
                    const v2f* xv = (const v2f*)(xc + t * 16);
                    v2f aA0 = {0.f, 0.f}, aA1 = {0.f, 0.f};
                    v2f aB0 = {0.f, 0.f}, aB1 = {0.f, 0.f};
                    if (wv == 1) {
#define GFMA1(i) { const v2f x2 = xv[i]; \
                   if ((i) & 1) { aA1 += A##i * x2; aB1 += B##i * x2; } \
                   else         { aA0 += A##i * x2; aB0 += B##i * x2; } }
                        REP32(GFMA1)
                        gp[t * 192 + lane] = aA0.x + aA0.y + aA1.x + aA1.y + sc0;
                        gp[t * 192 + 128 + lane] = aB0.x + aB0.y + aB1.x + aB1.y + sc1;
                    } else {
#define GFMA2(i) { const v2f x2 = xv[i]; \
                   if ((i) & 1) { aA1 += A##i * x2; } \
                   else         { aA0 += A##i * x2; } }
                        REP32(GFMA2)
                        gp[t * 192 + 64 + lane] = aA0.x + aA0.y + aA1.x + aA1.y + sc0;
                    }
                }
            }
        } else {
            // ---- epilogue for chunk p-2: LN over 16 timesteps, 2 halves of 8 ----
            if (p >= 2) {
                const int ce = p - 2;
                const float* hp = (const float*)hist[ce & 1];
#pragma unroll
                for (int half = 0; half < 2; ++half) {
                    float yv[8], sv[8], qv[8];
#pragma unroll
                    for (int u = 0; u < 8; ++u) {
                        const int t = half * 8 + u;
                        const v2f* hr = (const v2f*)(hp + t * HID);
                        v2f a20 = {0.f, 0.f}, a21 = {0.f, 0.f};
#define EFMA(i) { const v2f h2 = hr[i]; \
                  if ((i) & 1) { a21 += A##i * h2; } else { a20 += A##i * h2; } }
                        REP32(EFMA)
                        yv[u] = sc0 + a20.x + a20.y + a21.x + a21.y;
                    }
#pragma unroll
                    for (int u = 0; u < 8; ++u) { sv[u] = yv[u]; qv[u] = yv[u] * yv[u]; }
                    // 16 independent shuffle streams per level -> latency overlaps
#pragma unroll
                    for (int m = 32; m >= 1; m >>= 1) {
#pragma unroll
                        for (int u = 0; u < 8; ++u) sv[u] += __shfl_xor(sv[u], m, 64);
#pragma unroll
                        for (int u = 0; u < 8; ++u) qv[u] += __shfl_xor(qv[u], m, 64);
                    }
#pragma unroll
                    for (int u = 0; u < 8; ++u) {
                        const int t = half * 8 + u;
                        const float mean = sv[u] * (1.0f / 64.0f);
                        const float var = qv[u] * (1.0f / 64.0f) - mean * mean;
                        const float dd = yv[u] - mean;
                        xb[(size_t)(ce * CH + t) * HID + lane] =
                            dd * rsqrtf(var + EPSN) * sc1 + sc2;
                    }
                }
            }
            // prefetch x chunk p+1
            if (p + 1 < NCH) {
                const float4* src = (const float4*)(xb + (size_t)(p + 1) * CH * HID);
                float4* dst = (float4*)xbuf[(p + 1) & 1];
#pragma unroll
                for (int q2 = 0; q2 < 4; ++q2) dst[lane + q2 * 64] = src[lane + q2 * 64];
            }
        }
        __syncthreads();
    }
}

extern "C" void kernel_launch(void* const* d_in, const int* in_sizes, int n_in,
                              void* d_out, int out_size, void* d_ws, size_t ws_size,
                              hipStream_t stream) {
    const float* ce  = (const float*)d_in[0];
    const float* w1  = (const float*)d_in[1];
    const float* b1  = (const float*)d_in[2];
    const float* g1  = (const float*)d_in[3];
    const float* be1 = (const float*)d_in[4];
    const float* Wih = (const float*)d_in[5];
    const float* bih = (const float*)d_in[6];
    const float* Whh = (const float*)d_in[7];
    const float* bhh = (const float*)d_in[8];
    const float* w2  = (const float*)d_in[9];
    const float* b2  = (const float*)d_in[10];
    const float* g2  = (const float*)d_in[11];
    const float* be2 = (const float*)d_in[12];
    float* out = (float*)d_out;

    const int nrows = in_sizes[0] / 6;   // B*T
    const int B = nrows / TST;           // 256

    k_inproj<<<(nrows + 3) / 4, 256, 0, stream>>>(ce, w1, b1, g1, be1, out, nrows);
    k_gru<<<B, 256, 0, stream>>>(out, Wih, bih, Whh, bhh, w2, b2, g2, be2);
}